// Round 13
// baseline (310.353 us; speedup 1.0000x reference)
//
#include <hip/hip_runtime.h>
#include <hip/hip_bf16.h>
#include <math.h>

#define NN   20000
#define INF  256
#define HID  256   // H*OUT = 4*64
#define NH   4
#define OUTF 64

__device__ __forceinline__ float lrelu(float x){ return x > 0.f ? x : 0.2f*x; }
__device__ __forceinline__ float elu(float x){ return x > 0.f ? x : __expf(x)-1.f; }
__device__ __forceinline__ ushort f2bf(float f){          // RNE, same as __float2bfloat16 for normals
    unsigned u = __float_as_uint(f);
    u += 0x7FFF + ((u >> 16) & 1);
    return (ushort)(u >> 16);
}
__device__ __forceinline__ void fma4(float4& a, float s, const float4& b){
    a.x = fmaf(s, b.x, a.x); a.y = fmaf(s, b.y, a.y);
    a.z = fmaf(s, b.z, a.z); a.w = fmaf(s, b.w, a.w);
}
__device__ __forceinline__ float dot4(float4 a, float4 b){
    return a.x*b.x + a.y*b.y + a.z*b.z + a.w*b.w;
}

// ---------------- CSR build ----------------
__global__ void k_deg_init(int* deg){
    int i = blockIdx.x*blockDim.x + threadIdx.x;
    if (i < NN) deg[i] = 1;               // self-loop
}

__global__ void k_deg_hist(const int* __restrict__ ei, int* deg, int E){
    int e = blockIdx.x*blockDim.x + threadIdx.x;
    if (e < E) atomicAdd(&deg[ei[E + e]], 1);   // dst = ei[1][e]
}

__global__ void k_scan(const int* __restrict__ deg, int* __restrict__ rowptr){
    __shared__ int part[1024];
    int t = threadIdx.x;
    const int CH = 20;                    // 1024*20 >= 20000
    int base = t*CH;
    int s = 0;
    for (int i = 0; i < CH; i++){ int idx = base+i; if (idx < NN) s += deg[idx]; }
    part[t] = s;
    __syncthreads();
    for (int off = 1; off < 1024; off <<= 1){
        int v = (t >= off) ? part[t-off] : 0;
        __syncthreads();
        part[t] += v;
        __syncthreads();
    }
    int run = (t > 0) ? part[t-1] : 0;
    for (int i = 0; i < CH; i++){
        int idx = base+i;
        if (idx < NN){ rowptr[idx] = run; run += deg[idx]; }
    }
    if (t == 1023) rowptr[NN] = part[1023];
}

__global__ void k_selfloop(const int* __restrict__ rowptr, int* col, int* cursor){
    int n = blockIdx.x*blockDim.x + threadIdx.x;
    if (n < NN){ int p = rowptr[n]; col[p] = n; cursor[n] = p+1; }
}

__global__ void k_scatter(const int* __restrict__ ei, int* cursor, int* col, int E){
    int e = blockIdx.x*blockDim.x + threadIdx.x;
    if (e < E){
        int s = ei[e], d = ei[E + e];
        int pos = atomicAdd(&cursor[d], 1);
        col[pos] = s;
    }
}

// ---------- Layer 1 GEMM + fused attention coefficients ----------
// 32-row tile, 256 threads = 4 waves (col-panel x row-half); each wave =
// 128 cols x 16 rows; thread = 4 cols x 8 rows (R=8, the proven ratio).
// Grid 625 -> ~2.4 blocks/CU x 4 waves = ~4.9 waves/SIMD (2x R12) to cover
// W-load latency at constant FMA:load mix.
__global__ void __launch_bounds__(256, 4)
k_gemm1(const float* __restrict__ x, const float* __restrict__ W,
        const float* __restrict__ att_s, const float* __restrict__ att_d,
        ushort* __restrict__ h1b, float* __restrict__ as1,
        float* __restrict__ ad1){
    __shared__ float xs[32][INF+4];       // 33.3 KB, pad breaks row aliasing
    int row0 = blockIdx.x*32;
    int t = threadIdx.x;
    for (int i = t; i < 32*(INF/4); i += 256){
        int r = i >> 6, kq = i & 63;
        ((float4*)&xs[r][0])[kq] = ((const float4*)(x + (size_t)(row0+r)*INF))[kq];
    }
    __syncthreads();
    int wave = t >> 6;
    int colp = wave & 1;      // col panel: 128 cols
    int rowh = wave >> 1;     // row half: 16 rows
    int lane = t & 63;
    int cq = lane & 31;       // 4 cols: c0..c0+3
    int rg = lane >> 5;       // 0..1 -> 8 rows each
    int c0 = colp*128 + cq*4;
    int r0 = rowh*16 + rg*8;
    const float* Wc = W + c0;
    float4 acc[8];
    #pragma unroll
    for (int r = 0; r < 8; r++) acc[r] = make_float4(0.f,0.f,0.f,0.f);
    for (int k4 = 0; k4 < INF; k4 += 4){
        float4 w0 = *(const float4*)(Wc + (size_t)(k4+0)*HID);
        float4 w1 = *(const float4*)(Wc + (size_t)(k4+1)*HID);
        float4 w2 = *(const float4*)(Wc + (size_t)(k4+2)*HID);
        float4 w3 = *(const float4*)(Wc + (size_t)(k4+3)*HID);
        #pragma unroll
        for (int r = 0; r < 8; r++){
            float4 xv = *(const float4*)(&xs[r0+r][k4]);
            fma4(acc[r], xv.x, w0); fma4(acc[r], xv.y, w1);
            fma4(acc[r], xv.z, w2); fma4(acc[r], xv.w, w3);
        }
    }
    float4 sv = *(const float4*)(att_s + c0);
    float4 dv = *(const float4*)(att_d + c0);
    int head = c0 >> 6;
    #pragma unroll
    for (int r = 0; r < 8; r++){
        int row = row0 + r0 + r;
        float ps = dot4(acc[r], sv);
        float pd = dot4(acc[r], dv);
        #pragma unroll
        for (int off = 1; off < 16; off <<= 1){     // reduce the 16 lanes of one head
            ps += __shfl_xor(ps, off, 64);
            pd += __shfl_xor(pd, off, 64);
        }
        ushort4 hb;
        hb.x = f2bf(acc[r].x); hb.y = f2bf(acc[r].y);
        hb.z = f2bf(acc[r].z); hb.w = f2bf(acc[r].w);
        *(ushort4*)(h1b + (size_t)row*HID + c0) = hb;
        if ((cq & 15) == 0){
            as1[row*NH + head] = ps;
            ad1[row*NH + head] = pd;
        }
    }
}

// ---------- layer-1 fused softmax+aggregate (single pass, bf16 gather) ----------
__global__ void k_agg1(const ushort* __restrict__ h1b, const int* __restrict__ rowptr,
                       const int* __restrict__ col, const float* __restrict__ as1,
                       const float* __restrict__ ad1, const float* __restrict__ bias,
                       float* __restrict__ x1){
    int wv = threadIdx.x >> 6, lane = threadIdx.x & 63;
    int n = blockIdx.x*4 + wv;
    if (n >= NN) return;
    int beg = rowptr[n], end = rowptr[n+1];
    float4 adst = ((const float4*)ad1)[n];
    int h = lane >> 4;
    float adh = h==0?adst.x : h==1?adst.y : h==2?adst.z : adst.w;
    float den = 0.f;
    float4 accs[4];
    #pragma unroll
    for (int u = 0; u < 4; u++) accs[u] = make_float4(0.f,0.f,0.f,0.f);

    for (int base = beg; base < end; base += 64){
        int cnt = min(64, end - base);
        int myidx = (lane < cnt) ? col[base + lane] : 0;
        int j = 0;
        for (; j + 8 <= cnt; j += 8){
            int ss[8];
            #pragma unroll
            for (int u = 0; u < 8; u++) ss[u] = __shfl(myidx, j+u, 64);
            uint2 hv[8];
            float aw[8];
            #pragma unroll
            for (int u = 0; u < 8; u++){
                hv[u] = *(const uint2*)(h1b + ((size_t)ss[u]<<8) + (lane<<2));
                aw[u] = as1[ss[u]*NH + h];
            }
            #pragma unroll
            for (int u = 0; u < 8; u++){
                float wexp = __expf(lrelu(aw[u]+adh));
                den += wexp;
                float f0 = __uint_as_float(hv[u].x << 16);
                float f1 = __uint_as_float(hv[u].x & 0xFFFF0000u);
                float f2 = __uint_as_float(hv[u].y << 16);
                float f3 = __uint_as_float(hv[u].y & 0xFFFF0000u);
                accs[u&3].x = fmaf(wexp, f0, accs[u&3].x);
                accs[u&3].y = fmaf(wexp, f1, accs[u&3].y);
                accs[u&3].z = fmaf(wexp, f2, accs[u&3].z);
                accs[u&3].w = fmaf(wexp, f3, accs[u&3].w);
            }
        }
        for (; j < cnt; j++){
            int s0 = __shfl(myidx, j, 64);
            uint2 hv0 = *(const uint2*)(h1b + ((size_t)s0<<8) + (lane<<2));
            float aw0 = as1[s0*NH + h];
            float wexp = __expf(lrelu(aw0+adh));
            den += wexp;
            accs[0].x = fmaf(wexp, __uint_as_float(hv0.x << 16),         accs[0].x);
            accs[0].y = fmaf(wexp, __uint_as_float(hv0.x & 0xFFFF0000u), accs[0].y);
            accs[0].z = fmaf(wexp, __uint_as_float(hv0.y << 16),         accs[0].z);
            accs[0].w = fmaf(wexp, __uint_as_float(hv0.y & 0xFFFF0000u), accs[0].w);
        }
    }
    float rs = 1.f/(den + 1e-16f);
    float4 b = ((const float4*)bias)[lane];
    float4 o;
    o.x = elu((accs[0].x+accs[1].x+accs[2].x+accs[3].x)*rs + b.x);
    o.y = elu((accs[0].y+accs[1].y+accs[2].y+accs[3].y)*rs + b.y);
    o.z = elu((accs[0].z+accs[1].z+accs[2].z+accs[3].z)*rs + b.z);
    o.w = elu((accs[0].w+accs[1].w+accs[2].w+accs[3].w)*rs + b.w);
    ((float4*)(x1 + (size_t)n*HID))[lane] = o;
}

// ---------- Layer 2 GEMM + fused attention coefficients ----------
// 32-row tile (grid=625); thread = 4 cols x 2 rows.
__global__ void k_gemm2(const float* __restrict__ x1, const float* __restrict__ W2,
                        const float* __restrict__ att_s, const float* __restrict__ att_d,
                        float* __restrict__ h2, float* __restrict__ a2s,
                        float* __restrict__ a2d){
    __shared__ float xs[32][HID];         // 32 KB
    int row0 = blockIdx.x*32;
    int t = threadIdx.x;
    for (int i = t; i < 32*(HID/4); i += 256){
        int r = i >> 6, kq = i & 63;
        ((float4*)&xs[r][0])[kq] = ((const float4*)(x1 + (size_t)(row0+r)*HID))[kq];
    }
    __syncthreads();
    int cg = t & 15;          // cols 4cg..4cg+3
    int rg = t >> 4;          // rows rg*2 .. rg*2+1
    const float* Wc = W2 + 4*cg;
    float4 acc[2];
    acc[0] = make_float4(0.f,0.f,0.f,0.f);
    acc[1] = make_float4(0.f,0.f,0.f,0.f);
    #pragma unroll 2
    for (int k4 = 0; k4 < HID; k4 += 4){
        float4 w0 = *(const float4*)(Wc + (size_t)(k4+0)*OUTF);
        float4 w1 = *(const float4*)(Wc + (size_t)(k4+1)*OUTF);
        float4 w2 = *(const float4*)(Wc + (size_t)(k4+2)*OUTF);
        float4 w3 = *(const float4*)(Wc + (size_t)(k4+3)*OUTF);
        #pragma unroll
        for (int r = 0; r < 2; r++){
            float4 xv = *(const float4*)(&xs[rg*2+r][k4]);
            fma4(acc[r], xv.x, w0); fma4(acc[r], xv.y, w1);
            fma4(acc[r], xv.z, w2); fma4(acc[r], xv.w, w3);
        }
    }
    float4 sv = *(const float4*)(att_s + 4*cg);
    float4 dv = *(const float4*)(att_d + 4*cg);
    #pragma unroll
    for (int r = 0; r < 2; r++){
        int row = row0 + rg*2 + r;
        float ps = dot4(acc[r], sv);
        float pd = dot4(acc[r], dv);
        #pragma unroll
        for (int off = 1; off < 16; off <<= 1){
            ps += __shfl_xor(ps, off, 64);
            pd += __shfl_xor(pd, off, 64);
        }
        *(float4*)(h2 + (size_t)row*OUTF + 4*cg) = acc[r];
        if (cg == 0){
            a2s[row] = ps;
            a2d[row] = pd;
        }
    }
}

// ---------- layer-2 fused softmax+aggregate (single pass, fp32) ----------
__global__ void k_agg2(const float* __restrict__ h2, const int* __restrict__ rowptr,
                       const int* __restrict__ col, const float* __restrict__ a2s,
                       const float* __restrict__ a2d, const float* __restrict__ bias2,
                       float* __restrict__ out){
    int wv = threadIdx.x >> 6, lane = threadIdx.x & 63;
    int n = blockIdx.x*4 + wv;
    if (n >= NN) return;
    int beg = rowptr[n], end = rowptr[n+1];
    float adh = a2d[n];
    float den = 0.f;
    float acc[4] = {0.f, 0.f, 0.f, 0.f};
    for (int base = beg; base < end; base += 64){
        int cnt = min(64, end - base);
        int myidx = (lane < cnt) ? col[base + lane] : 0;
        int j = 0;
        for (; j + 8 <= cnt; j += 8){
            int ss[8];
            #pragma unroll
            for (int u = 0; u < 8; u++) ss[u] = __shfl(myidx, j+u, 64);
            float hw[8], aw[8];
            #pragma unroll
            for (int u = 0; u < 8; u++){
                hw[u] = h2[(size_t)ss[u]*OUTF + lane];
                aw[u] = a2s[ss[u]];
            }
            #pragma unroll
            for (int u = 0; u < 8; u++){
                float wexp = __expf(lrelu(aw[u]+adh));
                den += wexp;
                acc[u&3] = fmaf(wexp, hw[u], acc[u&3]);
            }
        }
        for (; j < cnt; j++){
            int s0 = __shfl(myidx, j, 64);
            float hv0 = h2[(size_t)s0*OUTF + lane];
            float w0 = __expf(lrelu(a2s[s0]+adh));
            den += w0;
            acc[0] = fmaf(w0, hv0, acc[0]);
        }
    }
    out[(size_t)n*OUTF + lane] = (acc[0]+acc[1]+acc[2]+acc[3])/(den + 1e-16f) + bias2[lane];
}

extern "C" void kernel_launch(void* const* d_in, const int* in_sizes, int n_in,
                              void* d_out, int out_size, void* d_ws, size_t ws_size,
                              hipStream_t stream){
    const float* x      = (const float*)d_in[0];
    const int*   ei     = (const int*)  d_in[1];
    const float* W1     = (const float*)d_in[2];
    const float* att_s1 = (const float*)d_in[3];
    const float* att_d1 = (const float*)d_in[4];
    const float* bias1  = (const float*)d_in[5];
    const float* W2     = (const float*)d_in[6];
    const float* att_s2 = (const float*)d_in[7];
    const float* att_d2 = (const float*)d_in[8];
    const float* bias2  = (const float*)d_in[9];
    int E = in_sizes[1] / 2;

    char* w = (char*)d_ws;
    size_t off = 0;
    auto alloc = [&](size_t b){ void* p = w + off; off += (b + 255) & ~(size_t)255; return p; };
    ushort* h1b   = (ushort*)alloc((size_t)NN*HID*2);
    float* x1     = (float*)alloc((size_t)NN*HID*4);
    float* h2     = (float*)alloc((size_t)NN*OUTF*4);
    float* as1    = (float*)alloc((size_t)NN*NH*4);
    float* ad1    = (float*)alloc((size_t)NN*NH*4);
    float* a2s    = (float*)alloc((size_t)NN*4);
    float* a2d    = (float*)alloc((size_t)NN*4);
    int*   deg    = (int*)alloc((size_t)(NN+1)*4);
    int*   rowptr = (int*)alloc((size_t)(NN+1)*4);
    int*   cursor = (int*)alloc((size_t)NN*4);
    int*   col    = (int*)alloc((size_t)(E+NN)*4);

    k_deg_init<<<(NN+255)/256, 256, 0, stream>>>(deg);
    k_deg_hist<<<(E+255)/256, 256, 0, stream>>>(ei, deg, E);
    k_scan<<<1, 1024, 0, stream>>>(deg, rowptr);
    k_selfloop<<<(NN+255)/256, 256, 0, stream>>>(rowptr, col, cursor);
    k_scatter<<<(E+255)/256, 256, 0, stream>>>(ei, cursor, col, E);

    k_gemm1<<<NN/32, 256, 0, stream>>>(x, W1, att_s1, att_d1, h1b, as1, ad1);
    k_agg1<<<(NN+3)/4, 256, 0, stream>>>(h1b, rowptr, col, as1, ad1, bias1, x1);

    k_gemm2<<<(NN+31)/32, 256, 0, stream>>>(x1, W2, att_s2, att_d2, h2, a2s, a2d);
    k_agg2<<<(NN+3)/4, 256, 0, stream>>>(h2, rowptr, col, a2s, a2d, bias2, (float*)d_out);
}

// Round 14
// 303.834 us; speedup vs baseline: 1.0215x; 1.0215x over previous
//
#include <hip/hip_runtime.h>
#include <hip/hip_bf16.h>
#include <math.h>

#define NN   20000
#define INF  256
#define HID  256   // H*OUT = 4*64
#define NH   4
#define OUTF 64

__device__ __forceinline__ float lrelu(float x){ return x > 0.f ? x : 0.2f*x; }
__device__ __forceinline__ float elu(float x){ return x > 0.f ? x : __expf(x)-1.f; }
__device__ __forceinline__ ushort f2bf(float f){          // RNE, same as __float2bfloat16 for normals
    unsigned u = __float_as_uint(f);
    u += 0x7FFF + ((u >> 16) & 1);
    return (ushort)(u >> 16);
}
__device__ __forceinline__ void fma4(float4& a, float s, const float4& b){
    a.x = fmaf(s, b.x, a.x); a.y = fmaf(s, b.y, a.y);
    a.z = fmaf(s, b.z, a.z); a.w = fmaf(s, b.w, a.w);
}
__device__ __forceinline__ float dot4(float4 a, float4 b){
    return a.x*b.x + a.y*b.y + a.z*b.z + a.w*b.w;
}

// ---------------- CSR build ----------------
__global__ void k_deg_init(int* deg){
    int i = blockIdx.x*blockDim.x + threadIdx.x;
    if (i < NN) deg[i] = 1;               // self-loop
}

__global__ void k_deg_hist(const int* __restrict__ ei, int* deg, int E){
    int e = blockIdx.x*blockDim.x + threadIdx.x;
    if (e < E) atomicAdd(&deg[ei[E + e]], 1);   // dst = ei[1][e]
}

__global__ void k_scan(const int* __restrict__ deg, int* __restrict__ rowptr){
    __shared__ int part[1024];
    int t = threadIdx.x;
    const int CH = 20;                    // 1024*20 >= 20000
    int base = t*CH;
    int s = 0;
    for (int i = 0; i < CH; i++){ int idx = base+i; if (idx < NN) s += deg[idx]; }
    part[t] = s;
    __syncthreads();
    for (int off = 1; off < 1024; off <<= 1){
        int v = (t >= off) ? part[t-off] : 0;
        __syncthreads();
        part[t] += v;
        __syncthreads();
    }
    int run = (t > 0) ? part[t-1] : 0;
    for (int i = 0; i < CH; i++){
        int idx = base+i;
        if (idx < NN){ rowptr[idx] = run; run += deg[idx]; }
    }
    if (t == 1023) rowptr[NN] = part[1023];
}

__global__ void k_selfloop(const int* __restrict__ rowptr, int* col, int* cursor){
    int n = blockIdx.x*blockDim.x + threadIdx.x;
    if (n < NN){ int p = rowptr[n]; col[p] = n; cursor[n] = p+1; }
}

__global__ void k_scatter(const int* __restrict__ ei, int* cursor, int* col, int E){
    int e = blockIdx.x*blockDim.x + threadIdx.x;
    if (e < E){
        int s = ei[e], d = ei[E + e];
        int pos = atomicAdd(&cursor[d], 1);
        col[pos] = s;
    }
}

// ---------- Layer 1 GEMM + fused attention coefficients ----------
// K-SPLIT: 16-row tile, 4 waves = colp(2) x kh(2). Each wave: 128 cols x
// 16 rows x K-half(128). Thread = 4 cols x 8 rows (R=8, proven ratio; loads
// halve with K so FMA:load stays 8:1). Waves double to 5000 (~4.9/SIMD) —
// the only way to raise wave count at fixed R (R12/R13: 2500 waves = 2.4/SIMD
// regardless of block shape). kh=1 partials reduced via LDS.
__global__ void __launch_bounds__(256, 4)
k_gemm1(const float* __restrict__ x, const float* __restrict__ W,
        const float* __restrict__ att_s, const float* __restrict__ att_d,
        ushort* __restrict__ h1b, float* __restrict__ as1,
        float* __restrict__ ad1){
    __shared__ float xs[16][INF+4];       // 16.6 KB
    __shared__ float4 red4[8][128];       // 16 KB partials (kh=1 -> kh=0)
    int row0 = blockIdx.x*16;
    int t = threadIdx.x;
    for (int i = t; i < 16*(INF/4); i += 256){
        int r = i >> 6, kq = i & 63;
        ((float4*)&xs[r][0])[kq] = ((const float4*)(x + (size_t)(row0+r)*INF))[kq];
    }
    __syncthreads();
    int wave = t >> 6;
    int colp = wave & 1;      // 128-col panel
    int kh   = wave >> 1;     // K half: k in [kh*128, kh*128+128)
    int lane = t & 63;
    int cq = lane & 31;       // 4 cols: c0..c0+3
    int rg = lane >> 5;       // 0..1 -> 8 rows each
    int c0 = colp*128 + cq*4;
    int r0 = rg*8;
    const float* Wc = W + c0;
    float4 acc[8];
    #pragma unroll
    for (int r = 0; r < 8; r++) acc[r] = make_float4(0.f,0.f,0.f,0.f);
    int kbeg = kh*128, kend = kbeg + 128;
    for (int k4 = kbeg; k4 < kend; k4 += 4){
        float4 w0 = *(const float4*)(Wc + (size_t)(k4+0)*HID);
        float4 w1 = *(const float4*)(Wc + (size_t)(k4+1)*HID);
        float4 w2 = *(const float4*)(Wc + (size_t)(k4+2)*HID);
        float4 w3 = *(const float4*)(Wc + (size_t)(k4+3)*HID);
        #pragma unroll
        for (int r = 0; r < 8; r++){
            float4 xv = *(const float4*)(&xs[r0+r][k4]);
            fma4(acc[r], xv.x, w0); fma4(acc[r], xv.y, w1);
            fma4(acc[r], xv.z, w2); fma4(acc[r], xv.w, w3);
        }
    }
    if (kh == 1){
        #pragma unroll
        for (int r = 0; r < 8; r++) red4[r][t - 128] = acc[r];
    }
    __syncthreads();
    if (kh == 1) return;
    #pragma unroll
    for (int r = 0; r < 8; r++){
        float4 p = red4[r][t];            // kh=0: t in 0..127, same (c0,rows)
        acc[r].x += p.x; acc[r].y += p.y;
        acc[r].z += p.z; acc[r].w += p.w;
    }
    float4 sv = *(const float4*)(att_s + c0);
    float4 dv = *(const float4*)(att_d + c0);
    int head = c0 >> 6;
    #pragma unroll
    for (int r = 0; r < 8; r++){
        int row = row0 + r0 + r;
        float ps = dot4(acc[r], sv);
        float pd = dot4(acc[r], dv);
        #pragma unroll
        for (int off = 1; off < 16; off <<= 1){     // reduce the 16 lanes of one head
            ps += __shfl_xor(ps, off, 64);
            pd += __shfl_xor(pd, off, 64);
        }
        ushort4 hb;
        hb.x = f2bf(acc[r].x); hb.y = f2bf(acc[r].y);
        hb.z = f2bf(acc[r].z); hb.w = f2bf(acc[r].w);
        *(ushort4*)(h1b + (size_t)row*HID + c0) = hb;
        if ((cq & 15) == 0){
            as1[row*NH + head] = ps;
            ad1[row*NH + head] = pd;
        }
    }
}

// ---------- layer-1 fused softmax+aggregate (single pass, bf16 gather) ----------
__global__ void k_agg1(const ushort* __restrict__ h1b, const int* __restrict__ rowptr,
                       const int* __restrict__ col, const float* __restrict__ as1,
                       const float* __restrict__ ad1, const float* __restrict__ bias,
                       float* __restrict__ x1){
    int wv = threadIdx.x >> 6, lane = threadIdx.x & 63;
    int n = blockIdx.x*4 + wv;
    if (n >= NN) return;
    int beg = rowptr[n], end = rowptr[n+1];
    float4 adst = ((const float4*)ad1)[n];
    int h = lane >> 4;
    float adh = h==0?adst.x : h==1?adst.y : h==2?adst.z : adst.w;
    float den = 0.f;
    float4 accs[4];
    #pragma unroll
    for (int u = 0; u < 4; u++) accs[u] = make_float4(0.f,0.f,0.f,0.f);

    for (int base = beg; base < end; base += 64){
        int cnt = min(64, end - base);
        int myidx = (lane < cnt) ? col[base + lane] : 0;
        int j = 0;
        for (; j + 8 <= cnt; j += 8){
            int ss[8];
            #pragma unroll
            for (int u = 0; u < 8; u++) ss[u] = __shfl(myidx, j+u, 64);
            uint2 hv[8];
            float aw[8];
            #pragma unroll
            for (int u = 0; u < 8; u++){
                hv[u] = *(const uint2*)(h1b + ((size_t)ss[u]<<8) + (lane<<2));
                aw[u] = as1[ss[u]*NH + h];
            }
            #pragma unroll
            for (int u = 0; u < 8; u++){
                float wexp = __expf(lrelu(aw[u]+adh));
                den += wexp;
                float f0 = __uint_as_float(hv[u].x << 16);
                float f1 = __uint_as_float(hv[u].x & 0xFFFF0000u);
                float f2 = __uint_as_float(hv[u].y << 16);
                float f3 = __uint_as_float(hv[u].y & 0xFFFF0000u);
                accs[u&3].x = fmaf(wexp, f0, accs[u&3].x);
                accs[u&3].y = fmaf(wexp, f1, accs[u&3].y);
                accs[u&3].z = fmaf(wexp, f2, accs[u&3].z);
                accs[u&3].w = fmaf(wexp, f3, accs[u&3].w);
            }
        }
        for (; j < cnt; j++){
            int s0 = __shfl(myidx, j, 64);
            uint2 hv0 = *(const uint2*)(h1b + ((size_t)s0<<8) + (lane<<2));
            float aw0 = as1[s0*NH + h];
            float wexp = __expf(lrelu(aw0+adh));
            den += wexp;
            accs[0].x = fmaf(wexp, __uint_as_float(hv0.x << 16),         accs[0].x);
            accs[0].y = fmaf(wexp, __uint_as_float(hv0.x & 0xFFFF0000u), accs[0].y);
            accs[0].z = fmaf(wexp, __uint_as_float(hv0.y << 16),         accs[0].z);
            accs[0].w = fmaf(wexp, __uint_as_float(hv0.y & 0xFFFF0000u), accs[0].w);
        }
    }
    float rs = 1.f/(den + 1e-16f);
    float4 b = ((const float4*)bias)[lane];
    float4 o;
    o.x = elu((accs[0].x+accs[1].x+accs[2].x+accs[3].x)*rs + b.x);
    o.y = elu((accs[0].y+accs[1].y+accs[2].y+accs[3].y)*rs + b.y);
    o.z = elu((accs[0].z+accs[1].z+accs[2].z+accs[3].z)*rs + b.z);
    o.w = elu((accs[0].w+accs[1].w+accs[2].w+accs[3].w)*rs + b.w);
    ((float4*)(x1 + (size_t)n*HID))[lane] = o;
}

// ---------- Layer 2 GEMM + fused attention coefficients ----------
// 32-row tile (grid=625); thread = 4 cols x 2 rows.
__global__ void k_gemm2(const float* __restrict__ x1, const float* __restrict__ W2,
                        const float* __restrict__ att_s, const float* __restrict__ att_d,
                        float* __restrict__ h2, float* __restrict__ a2s,
                        float* __restrict__ a2d){
    __shared__ float xs[32][HID];         // 32 KB
    int row0 = blockIdx.x*32;
    int t = threadIdx.x;
    for (int i = t; i < 32*(HID/4); i += 256){
        int r = i >> 6, kq = i & 63;
        ((float4*)&xs[r][0])[kq] = ((const float4*)(x1 + (size_t)(row0+r)*HID))[kq];
    }
    __syncthreads();
    int cg = t & 15;          // cols 4cg..4cg+3
    int rg = t >> 4;          // rows rg*2 .. rg*2+1
    const float* Wc = W2 + 4*cg;
    float4 acc[2];
    acc[0] = make_float4(0.f,0.f,0.f,0.f);
    acc[1] = make_float4(0.f,0.f,0.f,0.f);
    #pragma unroll 2
    for (int k4 = 0; k4 < HID; k4 += 4){
        float4 w0 = *(const float4*)(Wc + (size_t)(k4+0)*OUTF);
        float4 w1 = *(const float4*)(Wc + (size_t)(k4+1)*OUTF);
        float4 w2 = *(const float4*)(Wc + (size_t)(k4+2)*OUTF);
        float4 w3 = *(const float4*)(Wc + (size_t)(k4+3)*OUTF);
        #pragma unroll
        for (int r = 0; r < 2; r++){
            float4 xv = *(const float4*)(&xs[rg*2+r][k4]);
            fma4(acc[r], xv.x, w0); fma4(acc[r], xv.y, w1);
            fma4(acc[r], xv.z, w2); fma4(acc[r], xv.w, w3);
        }
    }
    float4 sv = *(const float4*)(att_s + 4*cg);
    float4 dv = *(const float4*)(att_d + 4*cg);
    #pragma unroll
    for (int r = 0; r < 2; r++){
        int row = row0 + rg*2 + r;
        float ps = dot4(acc[r], sv);
        float pd = dot4(acc[r], dv);
        #pragma unroll
        for (int off = 1; off < 16; off <<= 1){
            ps += __shfl_xor(ps, off, 64);
            pd += __shfl_xor(pd, off, 64);
        }
        *(float4*)(h2 + (size_t)row*OUTF + 4*cg) = acc[r];
        if (cg == 0){
            a2s[row] = ps;
            a2d[row] = pd;
        }
    }
}

// ---------- layer-2 fused softmax+aggregate (single pass, fp32) ----------
__global__ void k_agg2(const float* __restrict__ h2, const int* __restrict__ rowptr,
                       const int* __restrict__ col, const float* __restrict__ a2s,
                       const float* __restrict__ a2d, const float* __restrict__ bias2,
                       float* __restrict__ out){
    int wv = threadIdx.x >> 6, lane = threadIdx.x & 63;
    int n = blockIdx.x*4 + wv;
    if (n >= NN) return;
    int beg = rowptr[n], end = rowptr[n+1];
    float adh = a2d[n];
    float den = 0.f;
    float acc[4] = {0.f, 0.f, 0.f, 0.f};
    for (int base = beg; base < end; base += 64){
        int cnt = min(64, end - base);
        int myidx = (lane < cnt) ? col[base + lane] : 0;
        int j = 0;
        for (; j + 8 <= cnt; j += 8){
            int ss[8];
            #pragma unroll
            for (int u = 0; u < 8; u++) ss[u] = __shfl(myidx, j+u, 64);
            float hw[8], aw[8];
            #pragma unroll
            for (int u = 0; u < 8; u++){
                hw[u] = h2[(size_t)ss[u]*OUTF + lane];
                aw[u] = a2s[ss[u]];
            }
            #pragma unroll
            for (int u = 0; u < 8; u++){
                float wexp = __expf(lrelu(aw[u]+adh));
                den += wexp;
                acc[u&3] = fmaf(wexp, hw[u], acc[u&3]);
            }
        }
        for (; j < cnt; j++){
            int s0 = __shfl(myidx, j, 64);
            float hv0 = h2[(size_t)s0*OUTF + lane];
            float w0 = __expf(lrelu(a2s[s0]+adh));
            den += w0;
            acc[0] = fmaf(w0, hv0, acc[0]);
        }
    }
    out[(size_t)n*OUTF + lane] = (acc[0]+acc[1]+acc[2]+acc[3])/(den + 1e-16f) + bias2[lane];
}

extern "C" void kernel_launch(void* const* d_in, const int* in_sizes, int n_in,
                              void* d_out, int out_size, void* d_ws, size_t ws_size,
                              hipStream_t stream){
    const float* x      = (const float*)d_in[0];
    const int*   ei     = (const int*)  d_in[1];
    const float* W1     = (const float*)d_in[2];
    const float* att_s1 = (const float*)d_in[3];
    const float* att_d1 = (const float*)d_in[4];
    const float* bias1  = (const float*)d_in[5];
    const float* W2     = (const float*)d_in[6];
    const float* att_s2 = (const float*)d_in[7];
    const float* att_d2 = (const float*)d_in[8];
    const float* bias2  = (const float*)d_in[9];
    int E = in_sizes[1] / 2;

    char* w = (char*)d_ws;
    size_t off = 0;
    auto alloc = [&](size_t b){ void* p = w + off; off += (b + 255) & ~(size_t)255; return p; };
    ushort* h1b   = (ushort*)alloc((size_t)NN*HID*2);
    float* x1     = (float*)alloc((size_t)NN*HID*4);
    float* h2     = (float*)alloc((size_t)NN*OUTF*4);
    float* as1    = (float*)alloc((size_t)NN*NH*4);
    float* ad1    = (float*)alloc((size_t)NN*NH*4);
    float* a2s    = (float*)alloc((size_t)NN*4);
    float* a2d    = (float*)alloc((size_t)NN*4);
    int*   deg    = (int*)alloc((size_t)(NN+1)*4);
    int*   rowptr = (int*)alloc((size_t)(NN+1)*4);
    int*   cursor = (int*)alloc((size_t)NN*4);
    int*   col    = (int*)alloc((size_t)(E+NN)*4);

    k_deg_init<<<(NN+255)/256, 256, 0, stream>>>(deg);
    k_deg_hist<<<(E+255)/256, 256, 0, stream>>>(ei, deg, E);
    k_scan<<<1, 1024, 0, stream>>>(deg, rowptr);
    k_selfloop<<<(NN+255)/256, 256, 0, stream>>>(rowptr, col, cursor);
    k_scatter<<<(E+255)/256, 256, 0, stream>>>(ei, cursor, col, E);

    k_gemm1<<<NN/16, 256, 0, stream>>>(x, W1, att_s1, att_d1, h1b, as1, ad1);
    k_agg1<<<(NN+3)/4, 256, 0, stream>>>(h1b, rowptr, col, as1, ad1, bias1, x1);

    k_gemm2<<<(NN+31)/32, 256, 0, stream>>>(x1, W2, att_s2, att_d2, h2, a2s, a2d);
    k_agg2<<<(NN+3)/4, 256, 0, stream>>>(h2, rowptr, col, a2s, a2d, bias2, (float*)d_out);
}